// Round 1
// baseline (592.436 us; speedup 1.0000x reference)
//
#include <hip/hip_runtime.h>
#include <hip/hip_bf16.h>

#define BINS 100
#define DIM 768
#define TPB 64        // tokens per block
#define NTHREADS 256
#define KPAD 128      // BINS padded to MFMA K multiple
#define PITCH 136     // ushort pitch for LDS bf16 rows: 272B = 16B-aligned, 2-way-bank (free)
#define CHUNK 64      // output columns per staging chunk
#define NCHUNK 12     // 768 / 64

typedef __attribute__((ext_vector_type(8))) short bf16x8;
typedef __attribute__((ext_vector_type(4))) float f32x4;

__device__ __forceinline__ unsigned short f2bf(float x) {
    __hip_bfloat16 h = __float2bfloat16(x);
    return *reinterpret_cast<unsigned short*>(&h);
}

__global__ __launch_bounds__(NTHREADS, 2)
void ead_kernel(const float* __restrict__ gene,
                const int*   __restrict__ pad_mask,
                const int*   __restrict__ masked_mask,
                const float* __restrict__ w1,
                const float* __restrict__ b1,
                const float* __restrict__ w2,
                const float* __restrict__ b2,
                const float* __restrict__ emb,
                const float* __restrict__ pad_emb,
                const float* __restrict__ mask_emb,
                float* __restrict__ out,
                int T)
{
    __shared__ float v2s[TPB][BINS];           // 25.6 KB (aliased by et in GEMM phase)
    __shared__ float v3s[TPB][BINS];           // 25.6 KB
    __shared__ unsigned short wbf[TPB][PITCH]; // 17.4 KB bf16 softmax weights, K-padded
    __shared__ float xs[TPB];
    __shared__ int surv[TPB];
    __shared__ unsigned char ovr[TPB];
    __shared__ float pmax[TPB][4];
    __shared__ float psum[TPB][4];
    __shared__ int Ssh;

    // E-chunk staging buffer aliases v2s (17.4 KB <= 25.6 KB), transposed: et[col][k]
    unsigned short (*et)[PITCH] = reinterpret_cast<unsigned short (*)[PITCH]>(&v2s[0][0]);

    const int tid  = threadIdx.x;
    const int lane = tid & 63;
    const int wave = tid >> 6;
    const long t0  = (long)blockIdx.x * TPB;
    const int nvalid = min(TPB, T - (int)t0);

    // ---- step 1: masks, survivor compaction (wave 0 covers all 64 tokens) ----
    if (wave == 0) {
        int o = 3; // out-of-range: neither computed nor written
        if (lane < nvalid) {
            int pm  = pad_mask[t0 + lane];
            int msk = masked_mask[t0 + lane];
            o = msk ? 2 : (pm ? 1 : 0);
            xs[lane] = gene[t0 + lane];
        }
        ovr[lane] = (unsigned char)o;
        unsigned long long ball = __ballot(o == 0);
        int slot = __popcll(ball & ((1ull << lane) - 1ull));
        if (o == 0) surv[slot] = lane;
        if (lane == 0) Ssh = __popcll(ball);
    }
    __syncthreads();
    const int S = Ssh;

    // ---- step 1.5: write overridden rows now (stores drain under later compute) ----
    {
        float pev[3], mev[3];
        #pragma unroll
        for (int q = 0; q < 3; q++) {
            int d = tid + q * NTHREADS;
            pev[q] = __bfloat162float(__float2bfloat16(pad_emb[d]));
            mev[q] = __bfloat162float(__float2bfloat16(mask_emb[d]));
        }
        for (int i = 0; i < TPB; i++) {
            int o = ovr[i];
            if (o == 1 || o == 2) {
                float* orow = out + (t0 + i) * (long)DIM;
                #pragma unroll
                for (int q = 0; q < 3; q++)
                    orow[tid + q * NTHREADS] = (o == 2) ? mev[q] : pev[q];
            }
        }
    }

    // ---- step 2: v2 = leaky_relu(x*w1 + b1) for survivors ----
    for (int idx = tid; idx < S * KPAD; idx += NTHREADS) {
        int s = idx >> 7, j = idx & (KPAD - 1);
        if (j < BINS) {
            float x = xs[surv[s]];
            float v = fmaf(x, w1[j], b1[j]);
            v2s[s][j] = v > 0.f ? v : 0.1f * v;
        }
    }
    __syncthreads();

    // ---- step 3: v3 = v2 + b2 + v2 @ w2^T (fp32, 4s x 4j register tiles) ----
    {
        int stiles = ((S <= 16) ? 16 : (S <= 32) ? 32 : 64) >> 2;
        int sshift = (S <= 16) ? 2 : (S <= 32) ? 3 : 4;   // log2(stiles)
        int ntiles = stiles * 25;
        for (int tIdx = tid; tIdx < ntiles; tIdx += NTHREADS) {
            int st = (tIdx & (stiles - 1)) << 2;
            int jt = (tIdx >> sshift) << 2;
            float acc[4][4] = {};
            const float4* vr0 = (const float4*)&v2s[st + 0][0];
            const float4* vr1 = (const float4*)&v2s[st + 1][0];
            const float4* vr2 = (const float4*)&v2s[st + 2][0];
            const float4* vr3 = (const float4*)&v2s[st + 3][0];
            const float4* wr0 = (const float4*)(w2 + (jt + 0) * BINS);
            const float4* wr1 = (const float4*)(w2 + (jt + 1) * BINS);
            const float4* wr2 = (const float4*)(w2 + (jt + 2) * BINS);
            const float4* wr3 = (const float4*)(w2 + (jt + 3) * BINS);
            for (int k4 = 0; k4 < 25; k4++) {
                float4 av[4] = {vr0[k4], vr1[k4], vr2[k4], vr3[k4]};
                float4 bv[4] = {wr0[k4], wr1[k4], wr2[k4], wr3[k4]};
                #pragma unroll
                for (int si = 0; si < 4; si++)
                    #pragma unroll
                    for (int jj = 0; jj < 4; jj++)
                        acc[si][jj] += av[si].x * bv[jj].x + av[si].y * bv[jj].y
                                     + av[si].z * bv[jj].z + av[si].w * bv[jj].w;
            }
            #pragma unroll
            for (int si = 0; si < 4; si++) {
                int s = st + si;
                if (s < S) {
                    #pragma unroll
                    for (int jj = 0; jj < 4; jj++) {
                        int j = jt + jj;
                        v3s[s][j] = v2s[s][j] + b2[j] + acc[si][jj];
                    }
                }
            }
        }
    }
    __syncthreads();

    // ---- step 4: softmax over bins, emit bf16 weights into wbf (K-padded) ----
    {
        int s = tid >> 2, part = tid & 3;
        int j0 = part * 25;
        if (s < S) {
            float m = -1e30f;
            for (int j = j0; j < j0 + 25; j++) m = fmaxf(m, v3s[s][j]);
            pmax[s][part] = m;
        }
        __syncthreads();
        if (s < S) {
            float m = fmaxf(fmaxf(pmax[s][0], pmax[s][1]), fmaxf(pmax[s][2], pmax[s][3]));
            float sum = 0.f;
            for (int j = j0; j < j0 + 25; j++) {
                float e = __expf(v3s[s][j] - m);
                v3s[s][j] = e;
                sum += e;
            }
            psum[s][part] = sum;
        }
        __syncthreads();
        if (s < S) {
            float inv = 1.f / (psum[s][0] + psum[s][1] + psum[s][2] + psum[s][3]);
            for (int j = j0; j < j0 + 25; j++)
                wbf[s][j] = f2bf(v3s[s][j] * inv);
            if (part == 3)
                for (int j = BINS; j < KPAD; j++) wbf[s][j] = 0;
        }
    }
    __syncthreads();

    // ---- step 5: GEMM (S x 128) @ (128 x 768) via MFMA 16x16x32 bf16 ----
    const int SM = (S + 15) >> 4;     // M-tiles of 16 slots
    const int arow = lane & 15;
    const int kgrp = lane >> 4;
    bf16x8 afr[4][4];                 // [m-tile][k-step], statically indexed
    #pragma unroll
    for (int m = 0; m < 4; m++) {
        if (m < SM) {
            #pragma unroll
            for (int ks = 0; ks < 4; ks++)
                afr[m][ks] = *(const bf16x8*)&wbf[m * 16 + arow][ks * 32 + kgrp * 8];
        }
    }

    for (int c = 0; c < NCHUNK; c++) {
        __syncthreads();  // previous chunk's B-frag reads (or step-3 v2s reads) done
        // stage E[:, c*64 .. c*64+63] transposed bf16 into et[col][k], zero K-pad
        for (int idx = tid; idx < CHUNK * 64; idx += NTHREADS) {
            int cc = idx & 63, kk = idx >> 6;
            int k0 = kk * 2;
            float e0 = (k0 < BINS)     ? emb[(long)k0 * DIM + c * CHUNK + cc]       : 0.f;
            float e1 = (k0 + 1 < BINS) ? emb[(long)(k0 + 1) * DIM + c * CHUNK + cc] : 0.f;
            unsigned int pk = (unsigned int)f2bf(e0) | ((unsigned int)f2bf(e1) << 16);
            *reinterpret_cast<unsigned int*>(&et[cc][k0]) = pk;
        }
        __syncthreads();
        if (SM > 0) {
            int colc = wave * 16 + arow;      // this wave's 16-col n-subtile
            bf16x8 bfr[4];
            #pragma unroll
            for (int ks = 0; ks < 4; ks++)
                bfr[ks] = *(const bf16x8*)&et[colc][ks * 32 + kgrp * 8];
            int dcol = c * CHUNK + colc;
            #pragma unroll
            for (int m = 0; m < 4; m++) {
                if (m < SM) {
                    f32x4 a = {0.f, 0.f, 0.f, 0.f};
                    #pragma unroll
                    for (int ks = 0; ks < 4; ks++)
                        a = __builtin_amdgcn_mfma_f32_16x16x32_bf16(afr[m][ks], bfr[ks], a, 0, 0, 0);
                    #pragma unroll
                    for (int r = 0; r < 4; r++) {
                        int slot = m * 16 + kgrp * 4 + r;
                        if (slot < S) {
                            int token = surv[slot];
                            out[(t0 + token) * (long)DIM + dcol] = a[r];
                        }
                    }
                }
            }
        }
    }
}

extern "C" void kernel_launch(void* const* d_in, const int* in_sizes, int n_in,
                              void* d_out, int out_size, void* d_ws, size_t ws_size,
                              hipStream_t stream) {
    const float* gene  = (const float*)d_in[0];
    const int*   pm    = (const int*)  d_in[1];
    const int*   mm    = (const int*)  d_in[2];
    const float* w1    = (const float*)d_in[3];
    const float* b1    = (const float*)d_in[4];
    const float* w2    = (const float*)d_in[5];
    const float* b2    = (const float*)d_in[6];
    const float* emb   = (const float*)d_in[7];
    const float* pade  = (const float*)d_in[8];
    const float* maske = (const float*)d_in[9];
    float* out = (float*)d_out;

    int T = in_sizes[0];                       // 8 * 19264 = 154112 tokens
    int nblk = (T + TPB - 1) / TPB;            // 2408
    hipLaunchKernelGGL(ead_kernel, dim3(nblk), dim3(NTHREADS), 0, stream,
                       gene, pm, mm, w1, b1, w2, b2, emb, pade, maske, out, T);
}

// Round 2
// 349.484 us; speedup vs baseline: 1.6952x; 1.6952x over previous
//
#include <hip/hip_runtime.h>
#include <hip/hip_bf16.h>

#define BINS 100
#define DIM 768
#define TPB 64        // tokens per block
#define NTHREADS 256
#define KPAD 128      // BINS padded to MFMA K multiple
#define PITCH 136     // ushort pitch for wbf rows: 272B = 16B-aligned, 2-way bank (free)
#define NCHUNK 12     // 768 / 64 output column chunks

typedef __attribute__((ext_vector_type(8))) short bf16x8;
typedef __attribute__((ext_vector_type(4))) float f32x4;

__device__ __forceinline__ unsigned short f2bf(float x) {
    __hip_bfloat16 h = __float2bfloat16(x);
    return *reinterpret_cast<unsigned short*>(&h);
}
__device__ __forceinline__ float bfrt(float x) {   // bf16 round-trip (RNE)
    return __bfloat162float(__float2bfloat16(x));
}

// one-time: ET[d][k] = bf16(emb[k][d]), k >= BINS zero-padded. 768 blocks x 128 thr.
__global__ void prep_et(const float* __restrict__ emb, unsigned short* __restrict__ et) {
    int d = blockIdx.x;
    int k = threadIdx.x;
    float v = (k < BINS) ? emb[(long)k * DIM + d] : 0.f;
    et[d * KPAD + k] = f2bf(v);
}

__global__ __launch_bounds__(NTHREADS, 4)
void ead_kernel(const float* __restrict__ gene,
                const int*   __restrict__ pad_mask,
                const int*   __restrict__ masked_mask,
                const float* __restrict__ w1,
                const float* __restrict__ b1,
                const float* __restrict__ w2,
                const float* __restrict__ b2,
                const unsigned short* __restrict__ et,
                const float* __restrict__ pad_emb,
                const float* __restrict__ mask_emb,
                float* __restrict__ out,
                int T)
{
    __shared__ unsigned short wbf[TPB][PITCH]; // 17.4 KB bf16 softmax weights, K-padded
    __shared__ float xs[TPB];
    __shared__ int surv[TPB];
    __shared__ unsigned char ovr[TPB];
    __shared__ int Ssh;

    const int tid  = threadIdx.x;
    const int lane = tid & 63;
    const int wave = tid >> 6;
    const long t0  = (long)blockIdx.x * TPB;
    const int nvalid = min(TPB, (int)(T - t0));

    // ---- step 1: masks, survivor compaction (wave 0) ----
    if (wave == 0) {
        int o = 3; // out-of-range: neither computed nor written
        if (lane < nvalid) {
            int pm  = pad_mask[t0 + lane];
            int msk = masked_mask[t0 + lane];
            o = msk ? 2 : (pm ? 1 : 0);
            xs[lane] = gene[t0 + lane];
        }
        ovr[lane] = (unsigned char)o;
        unsigned long long ball = __ballot(o == 0);
        int slot = __popcll(ball & ((1ull << lane) - 1ull));
        if (o == 0) surv[slot] = lane;
        if (lane == 0) Ssh = __popcll(ball);
    }
    __syncthreads();
    const int S = Ssh;

    // ---- step 1.5: write overridden rows now (drain under later compute) ----
    {
        float4 pev = {0,0,0,0}, mev = {0,0,0,0};
        if (tid < 192) {
            float4 p = ((const float4*)pad_emb)[tid];
            float4 m = ((const float4*)mask_emb)[tid];
            pev = make_float4(bfrt(p.x), bfrt(p.y), bfrt(p.z), bfrt(p.w));
            mev = make_float4(bfrt(m.x), bfrt(m.y), bfrt(m.z), bfrt(m.w));
        }
        for (int i = 0; i < TPB; i++) {
            int o = ovr[i];
            if ((o == 1 || o == 2) && tid < 192) {
                float4* orow = (float4*)(out + (t0 + i) * (long)DIM);
                orow[tid] = (o == 2) ? mev : pev;
            }
        }
    }

    // ---- steps 2-4 fused: token slot s handled by 4 lanes (part 0..3) ----
    // v2 recomputed on the fly (no LDS); v3 accumulated in registers; softmax
    // via 4-lane shuffle reduce; bf16 weights -> wbf.
    {
        int s = tid >> 2, part = tid & 3;
        if (s < S) {
            float x = xs[surv[s]];
            const int j0 = part * 25;
            float acc[25];
            #pragma unroll
            for (int i = 0; i < 25; i++) acc[i] = 0.f;
            for (int k4 = 0; k4 < 25; k4++) {
                float4 w1v = ((const float4*)w1)[k4];
                float4 b1v = ((const float4*)b1)[k4];
                float4 v;
                v.x = fmaf(x, w1v.x, b1v.x); v.x = v.x > 0.f ? v.x : 0.1f * v.x;
                v.y = fmaf(x, w1v.y, b1v.y); v.y = v.y > 0.f ? v.y : 0.1f * v.y;
                v.z = fmaf(x, w1v.z, b1v.z); v.z = v.z > 0.f ? v.z : 0.1f * v.z;
                v.w = fmaf(x, w1v.w, b1v.w); v.w = v.w > 0.f ? v.w : 0.1f * v.w;
                #pragma unroll
                for (int i = 0; i < 25; i++) {
                    float4 wv = *(const float4*)(w2 + (j0 + i) * BINS + k4 * 4);
                    acc[i] += v.x * wv.x + v.y * wv.y + v.z * wv.z + v.w * wv.w;
                }
            }
            float vmax = -1e30f;
            #pragma unroll
            for (int i = 0; i < 25; i++) {
                int j = j0 + i;
                float vj = fmaf(x, w1[j], b1[j]); vj = vj > 0.f ? vj : 0.1f * vj;
                acc[i] += vj + b2[j];
                vmax = fmaxf(vmax, acc[i]);
            }
            vmax = fmaxf(vmax, __shfl_xor(vmax, 1));
            vmax = fmaxf(vmax, __shfl_xor(vmax, 2));
            float sum = 0.f;
            #pragma unroll
            for (int i = 0; i < 25; i++) {
                acc[i] = __expf(acc[i] - vmax);
                sum += acc[i];
            }
            sum += __shfl_xor(sum, 1);
            sum += __shfl_xor(sum, 2);
            float inv = 1.f / sum;
            #pragma unroll
            for (int i = 0; i < 25; i++)
                wbf[s][j0 + i] = f2bf(acc[i] * inv);
            if (part == 3) {
                #pragma unroll
                for (int j = BINS; j < KPAD; j += 2)
                    *reinterpret_cast<unsigned int*>(&wbf[s][j]) = 0u;
            }
        }
    }
    __syncthreads();

    // ---- step 5: (S x 128) @ ET^T via MFMA 16x16x32 bf16, B straight from L2 ----
    const int SM = (S + 15) >> 4;
    if (SM > 0) {
        const int arow = lane & 15;
        const int kgrp = lane >> 4;
        bf16x8 afr[4][4];
        int tok[4][4];
        #pragma unroll
        for (int m = 0; m < 4; m++) {
            if (m < SM) {
                #pragma unroll
                for (int ks = 0; ks < 4; ks++)
                    afr[m][ks] = *(const bf16x8*)&wbf[m * 16 + arow][ks * 32 + kgrp * 8];
                #pragma unroll
                for (int r = 0; r < 4; r++) {
                    int slot = m * 16 + kgrp * 4 + r;
                    tok[m][r] = (slot < S) ? surv[slot] : -1;
                }
            }
        }
        for (int c = 0; c < NCHUNK; c++) {
            int dcol = c * 64 + wave * 16 + arow;
            const unsigned short* bp = et + dcol * KPAD + kgrp * 8;
            bf16x8 bfr[4];
            #pragma unroll
            for (int ks = 0; ks < 4; ks++)
                bfr[ks] = *(const bf16x8*)(bp + ks * 32);
            #pragma unroll
            for (int m = 0; m < 4; m++) {
                if (m < SM) {
                    f32x4 a = {0.f, 0.f, 0.f, 0.f};
                    #pragma unroll
                    for (int ks = 0; ks < 4; ks++)
                        a = __builtin_amdgcn_mfma_f32_16x16x32_bf16(afr[m][ks], bfr[ks], a, 0, 0, 0);
                    #pragma unroll
                    for (int r = 0; r < 4; r++) {
                        int t = tok[m][r];
                        if (t >= 0)
                            out[(t0 + t) * (long)DIM + dcol] = a[r];
                    }
                }
            }
        }
    }
}

extern "C" void kernel_launch(void* const* d_in, const int* in_sizes, int n_in,
                              void* d_out, int out_size, void* d_ws, size_t ws_size,
                              hipStream_t stream) {
    const float* gene  = (const float*)d_in[0];
    const int*   pm    = (const int*)  d_in[1];
    const int*   mm    = (const int*)  d_in[2];
    const float* w1    = (const float*)d_in[3];
    const float* b1    = (const float*)d_in[4];
    const float* w2    = (const float*)d_in[5];
    const float* b2    = (const float*)d_in[6];
    const float* emb   = (const float*)d_in[7];
    const float* pade  = (const float*)d_in[8];
    const float* maske = (const float*)d_in[9];
    float* out = (float*)d_out;
    unsigned short* et = (unsigned short*)d_ws;   // DIM*KPAD*2 = 196,608 B

    int T = in_sizes[0];                          // 8 * 19264 = 154112 tokens
    int nblk = (T + TPB - 1) / TPB;               // 2408

    hipLaunchKernelGGL(prep_et, dim3(DIM), dim3(KPAD), 0, stream, emb, et);
    hipLaunchKernelGGL(ead_kernel, dim3(nblk), dim3(NTHREADS), 0, stream,
                       gene, pm, mm, w1, b1, w2, b2, et, pade, maske, out, T);
}

// Round 3
// 193.617 us; speedup vs baseline: 3.0598x; 1.8050x over previous
//
#include <hip/hip_runtime.h>
#include <hip/hip_bf16.h>

#define BINS 100
#define DIM 768
#define TPB 64        // tokens per block
#define NTHREADS 256
#define KPAD 128      // BINS padded to MFMA K multiple
#define PITCH 136     // ushort pitch for wbf rows: 272B, 16B-aligned
#define NDT 12        // d-tiles (16 cols) per wave: 48 tiles / 4 waves

// workspace byte offsets
#define OFF_ET   0         // ushort[768*128] = 196608 B
#define OFF_P    196608    // float[100] (512 B reserved)
#define OFF_Q    197120
#define OFF_TS   197632
#define OFF_KS   198144    // int[100]
#define OFF_R    198656    // int
#define OFF_W2P  198720    // float[100*100] = 40000 B  (end 238720)

typedef __attribute__((ext_vector_type(8))) short bf16x8;
typedef __attribute__((ext_vector_type(4))) float f32x4;

__device__ __forceinline__ unsigned short f2bf(float x) {
    __hip_bfloat16 h = __float2bfloat16(x);
    return *reinterpret_cast<unsigned short*>(&h);
}
__device__ __forceinline__ float bfrt(float x) {   // bf16 round-trip (RNE)
    return __bfloat162float(__float2bfloat16(x));
}

// grid = DIM+1 blocks x 128 threads. Blocks [0,DIM): transpose emb -> bf16 ET.
// Block DIM: build P,Q (collapsed linear map), w2p = w2 + I, sorted thresholds.
__global__ void prep(const float* __restrict__ emb,
                     const float* __restrict__ w1,
                     const float* __restrict__ b1,
                     const float* __restrict__ w2,
                     const float* __restrict__ b2,
                     unsigned char* __restrict__ ws)
{
    const int bid = blockIdx.x;
    const int tid = threadIdx.x;
    if (bid < DIM) {
        unsigned short* et = (unsigned short*)(ws + OFF_ET);
        float v = (tid < BINS) ? emb[(long)tid * DIM + bid] : 0.f;
        et[bid * KPAD + tid] = f2bf(v);
        return;
    }
    __shared__ float pl[BINS], ql[BINS], tl[BINS];
    float* Pv  = (float*)(ws + OFF_P);
    float* Qv  = (float*)(ws + OFF_Q);
    float* ts  = (float*)(ws + OFF_TS);
    int*   ks  = (int*)  (ws + OFF_KS);
    int*   Rp  = (int*)  (ws + OFF_R);
    float* w2p = (float*)(ws + OFF_W2P);
    if (tid < BINS) {
        float w = w1[tid], b = b1[tid];
        // branch taken as x -> +inf (the "common" branch for x in [0,10])
        float f = (w > 0.f || (w == 0.f && b > 0.f)) ? 1.f : 0.1f;
        pl[tid] = w * f;
        ql[tid] = b * f;
        tl[tid] = (w != 0.f) ? (-b / w) : -1.f;   // breakpoint; w==0 never flips
    }
    __syncthreads();
    if (tid < BINS) {
        const int j = tid;
        float P = pl[j];            // alpha=1 direct term
        float Q = ql[j] + b2[j];
        for (int k = 0; k < BINS; k++) {
            float w = w2[j * BINS + k];
            P = fmaf(w, pl[k], P);
            Q = fmaf(w, ql[k], Q);
            w2p[j * BINS + k] = w + (j == k ? 1.f : 0.f);   // matmul + alpha*I
        }
        Pv[j] = P; Qv[j] = Q;
        // rank-sort thresholds descending (positives first)
        float tk = tl[j];
        int rank = 0;
        for (int k2 = 0; k2 < BINS; k2++) {
            float t2 = tl[k2];
            rank += (t2 > tk || (t2 == tk && k2 < j)) ? 1 : 0;
        }
        ts[rank] = tk;
        ks[rank] = j;
    }
    if (tid == 0) {
        int R = 0;
        for (int k = 0; k < BINS; k++) R += (tl[k] > 0.f) ? 1 : 0;
        *Rp = R;
    }
}

__global__ __launch_bounds__(NTHREADS, 6)
void ead_kernel(const float* __restrict__ gene,
                const int*   __restrict__ pad_mask,
                const int*   __restrict__ masked_mask,
                const float* __restrict__ w1,
                const float* __restrict__ b1,
                const unsigned short* __restrict__ et,
                const float* __restrict__ Pv,
                const float* __restrict__ Qv,
                const float* __restrict__ ts,
                const int*   __restrict__ ksod,
                const int*   __restrict__ Rp,
                const float* __restrict__ w2p,
                const float* __restrict__ pad_emb,
                const float* __restrict__ mask_emb,
                float* __restrict__ out,
                int T)
{
    __shared__ unsigned short wbf[TPB][PITCH]; // bf16 softmax weights, K-padded
    __shared__ float xs[TPB];
    __shared__ int surv[TPB];
    __shared__ int olist[TPB];
    __shared__ unsigned char ovr[TPB];
    __shared__ int Ssh, Osh;

    const int tid  = threadIdx.x;
    const int lane = tid & 63;
    const int wave = tid >> 6;
    const long t0  = (long)blockIdx.x * TPB;
    const int nvalid = min(TPB, (int)(T - t0));

    // ---- step 1: masks, survivor + override compaction (wave 0) ----
    if (wave == 0) {
        int o = 3; // out-of-range: neither computed nor written
        if (lane < nvalid) {
            int pm  = pad_mask[t0 + lane];
            int msk = masked_mask[t0 + lane];
            o = msk ? 2 : (pm ? 1 : 0);
            xs[lane] = gene[t0 + lane];
        }
        ovr[lane] = (unsigned char)o;
        unsigned long long bs = __ballot(o == 0);
        unsigned long long bo = __ballot(o == 1 || o == 2);
        int si = __popcll(bs & ((1ull << lane) - 1ull));
        int oi = __popcll(bo & ((1ull << lane) - 1ull));
        if (o == 0) surv[si] = lane;
        if (o == 1 || o == 2) olist[oi] = lane;
        if (lane == 0) { Ssh = __popcll(bs); Osh = __popcll(bo); }
    }
    __syncthreads();
    const int S = Ssh;

    // ---- step 1.5: write overridden rows (drain under later compute) ----
    {
        float4 pev = {0,0,0,0}, mev = {0,0,0,0};
        if (tid < 192) {
            float4 p = ((const float4*)pad_emb)[tid];
            float4 m = ((const float4*)mask_emb)[tid];
            pev = make_float4(bfrt(p.x), bfrt(p.y), bfrt(p.z), bfrt(p.w));
            mev = make_float4(bfrt(m.x), bfrt(m.y), bfrt(m.z), bfrt(m.w));
        }
        const int O = Osh;
        for (int i = 0; i < O; i++) {
            int row = olist[i];
            if (tid < 192) {
                float4* orow = (float4*)(out + (t0 + row) * (long)DIM);
                orow[tid] = (ovr[row] == 2) ? mev : pev;
            }
        }
    }

    // ---- steps 2-4 collapsed: v3 = x*P + Q + rare-bin corrections; softmax ----
    {
        int s = tid >> 2, part = tid & 3;
        const int j0 = part * 25;
        if (s < S) {
            float x = xs[surv[s]];
            float v3[25];
            #pragma unroll
            for (int i = 0; i < 25; i++)
                v3[i] = fmaf(x, Pv[j0 + i], Qv[j0 + i]);
            const int R = *Rp;
            for (int idx = 0; idx < R; ++idx) {
                float t = ts[idx];
                if (t <= x) break;              // sorted desc: rest are common
                int k = ksod[idx];
                float v1 = fmaf(x, w1[k], b1[k]);
                float d = 0.9f * fabsf(v1);     // (f_actual - f_common)*v1
                const float* wc = w2p + j0 * BINS + k;
                #pragma unroll
                for (int i = 0; i < 25; i++)
                    v3[i] = fmaf(wc[i * BINS], d, v3[i]);
            }
            float vmax = -1e30f;
            #pragma unroll
            for (int i = 0; i < 25; i++) vmax = fmaxf(vmax, v3[i]);
            vmax = fmaxf(vmax, __shfl_xor(vmax, 1));
            vmax = fmaxf(vmax, __shfl_xor(vmax, 2));
            float sum = 0.f;
            #pragma unroll
            for (int i = 0; i < 25; i++) {
                v3[i] = __expf(v3[i] - vmax);
                sum += v3[i];
            }
            sum += __shfl_xor(sum, 1);
            sum += __shfl_xor(sum, 2);
            float inv = 1.f / sum;
            #pragma unroll
            for (int i = 0; i < 25; i++)
                wbf[s][j0 + i] = f2bf(v3[i] * inv);
            if (part == 3) {
                #pragma unroll
                for (int j = BINS; j < KPAD; j += 2)
                    *reinterpret_cast<unsigned int*>(&wbf[s][j]) = 0u;
            }
        }
    }
    __syncthreads();

    // ---- step 5: MFMA with swapped operands: D[d][token] = ET @ W^T ----
    // A = ET rows (16 d-cols), B = wbf token weights -> lane holds 4 consecutive
    // d's of ONE token => float4 stores.
    const int SM = (S + 15) >> 4;
    if (SM > 0) {
        const int arow = lane & 15;
        const int kgrp = lane >> 4;
        int tok0 = -1, tok1 = -1, tok2 = -1, tok3 = -1;
        {
            int sl;
            sl = 0 * 16 + arow; tok0 = (sl < S) ? surv[sl] : -1;
            sl = 1 * 16 + arow; tok1 = (SM > 1 && sl < S) ? surv[sl] : -1;
            sl = 2 * 16 + arow; tok2 = (SM > 2 && sl < S) ? surv[sl] : -1;
            sl = 3 * 16 + arow; tok3 = (SM > 3 && sl < S) ? surv[sl] : -1;
        }
        for (int c = 0; c < NDT; c++) {
            int dt = (c * 4 + wave) * 16;          // this wave's 16-col d-tile
            const unsigned short* ap = et + (long)(dt + arow) * KPAD + kgrp * 8;
            bf16x8 afr[4];
            #pragma unroll
            for (int kss = 0; kss < 4; kss++)
                afr[kss] = *(const bf16x8*)(ap + kss * 32);
            #pragma unroll
            for (int mt = 0; mt < 4; mt++) {
                if (mt < SM) {
                    f32x4 a = {0.f, 0.f, 0.f, 0.f};
                    #pragma unroll
                    for (int kss = 0; kss < 4; kss++) {
                        bf16x8 bfr = *(const bf16x8*)&wbf[mt * 16 + arow][kss * 32 + kgrp * 8];
                        a = __builtin_amdgcn_mfma_f32_16x16x32_bf16(afr[kss], bfr, a, 0, 0, 0);
                    }
                    int tkn = (mt == 0) ? tok0 : (mt == 1) ? tok1 : (mt == 2) ? tok2 : tok3;
                    if (tkn >= 0)
                        *(float4*)(out + (t0 + tkn) * (long)DIM + dt + kgrp * 4)
                            = *reinterpret_cast<float4*>(&a);
                }
            }
        }
    }
}

extern "C" void kernel_launch(void* const* d_in, const int* in_sizes, int n_in,
                              void* d_out, int out_size, void* d_ws, size_t ws_size,
                              hipStream_t stream) {
    const float* gene  = (const float*)d_in[0];
    const int*   pm    = (const int*)  d_in[1];
    const int*   mm    = (const int*)  d_in[2];
    const float* w1    = (const float*)d_in[3];
    const float* b1    = (const float*)d_in[4];
    const float* w2    = (const float*)d_in[5];
    const float* b2    = (const float*)d_in[6];
    const float* emb   = (const float*)d_in[7];
    const float* pade  = (const float*)d_in[8];
    const float* maske = (const float*)d_in[9];
    float* out = (float*)d_out;
    unsigned char* ws = (unsigned char*)d_ws;

    int T = in_sizes[0];                          // 8 * 19264 = 154112 tokens
    int nblk = (T + TPB - 1) / TPB;               // 2408

    hipLaunchKernelGGL(prep, dim3(DIM + 1), dim3(KPAD), 0, stream,
                       emb, w1, b1, w2, b2, ws);
    hipLaunchKernelGGL(ead_kernel, dim3(nblk), dim3(NTHREADS), 0, stream,
                       gene, pm, mm, w1, b1,
                       (const unsigned short*)(ws + OFF_ET),
                       (const float*)(ws + OFF_P),
                       (const float*)(ws + OFF_Q),
                       (const float*)(ws + OFF_TS),
                       (const int*)(ws + OFF_KS),
                       (const int*)(ws + OFF_R),
                       (const float*)(ws + OFF_W2P),
                       pade, maske, out, T);
}